// Round 1
// baseline (349.367 us; speedup 1.0000x reference)
//
#include <hip/hip_runtime.h>

typedef unsigned short u16;
using bf16x8 = __attribute__((ext_vector_type(8))) short;
using f32x4  = __attribute__((ext_vector_type(4))) float;
using s16x4  = __attribute__((ext_vector_type(4))) short;

#define S_LEN 512
#define D_DIM 128
#define CB    64                     // kv chunk staged in LDS
#define KS    136                    // K LDS stride (shorts)
#define VS    68                     // VT LDS stride (shorts)
#define SCALE 0.08838834764831845f   // 1/sqrt(128)

// RNE f32 pair -> packed bf16x2 (hardware, 1 instr; same rounding as manual f2b)
__device__ __forceinline__ unsigned int cvt_pk_bf16(float lo, float hi) {
  unsigned int r;
  asm("v_cvt_pk_bf16_f32 %0, %1, %2" : "=v"(r) : "v"(lo), "v"(hi));
  return r;
}

__device__ __forceinline__ bf16x8 pack8(f32x4 a, f32x4 b) {
  union { unsigned int u[4]; bf16x8 v; } r;
  r.u[0] = cvt_pk_bf16(a[0], a[1]);
  r.u[1] = cvt_pk_bf16(a[2], a[3]);
  r.u[2] = cvt_pk_bf16(b[0], b[1]);
  r.u[3] = cvt_pk_bf16(b[2], b[3]);
  return r.v;
}

// fp32 in / fp32 out. S^T = K.Q^T (A=K from LDS, B=Q regs); PV with pi-permuted
// packing. T14 pipeline: chunk c+1's K/V global loads live in regs across the
// whole compute phase of chunk c. Raw s_barrier + lgkmcnt-only drains keep the
// prefetch vmcnt counted across barriers (plain __syncthreads would drain it).
__global__ __launch_bounds__(256, 3)
void attn_fused(const float* __restrict__ Q, const float* __restrict__ K,
                const float* __restrict__ V, const int* __restrict__ VL,
                const float* __restrict__ WM, float* __restrict__ O) {
  __shared__ short Ksh[CB * KS];     // Ksh[kv_local][d], bf16
  __shared__ short VT[D_DIM * VS];   // VT[d][kv_local], bf16, XOR-swizzled kv

  const int bid  = blockIdx.x;
  const int n    = (bid & 7) | ((bid >> 6) << 3);   // n%8 == bid%8 (XCD)
  const int qt   = (bid >> 3) & 7;
  const int tid  = threadIdx.x;
  const int wave = tid >> 6;
  const int L    = tid & 63;
  const int quad = L >> 4;
  const int lq   = L & 15;
  const int qw   = qt * 64 + wave * 16;   // wave's q base
  const int qg   = qw + lq;               // this lane's q row
  const int w    = (n >> 3) & 15;         // window index

  const float* Qn  = Q + (size_t)n * S_LEN * D_DIM;
  const float* Kn  = K + (size_t)n * S_LEN * D_DIM;
  const float* Vn  = V + (size_t)n * S_LEN * D_DIM;
  const float* WMq = WM + ((size_t)w * S_LEN + qg) * S_LEN;

  const int vlen  = VL[n];
  const int kvlim = (vlen == 0) ? S_LEN : vlen;
  const int nch   = (kvlim + CB - 1) / CB;          // 1..8 chunks

  // Q fragments (B-operand): lane holds Q[qg][dc*32 + quad*8 + j], j=0..7
  bf16x8 qf[4];
#pragma unroll
  for (int dc = 0; dc < 4; ++dc) {
    const f32x4* qp = (const f32x4*)(Qn + (size_t)qg * D_DIM + dc * 32 + quad * 8);
    qf[dc] = pack8(qp[0], qp[1]);
  }

  f32x4 o[8];
#pragma unroll
  for (int t = 0; t < 8; ++t) o[t] = (f32x4){0.f, 0.f, 0.f, 0.f};
  float mrun = -1e30f, lrun = 0.f;

  // ---- staging geometry: thread covers rows tr, tr+16, tr+32, tr+48 at d-chunk cc
  const int tr = tid >> 4;          // row-in-chunk base
  const int cc = tid & 15;          // 8-float d-chunk
  const float* Kst = Kn + (size_t)tr * D_DIM + cc * 8;
  const float* Vst = Vn + (size_t)tr * D_DIM + cc * 8;

  f32x4 pk[8], pv[8];               // prefetch regs: 64 VGPR, the pipeline depth
  auto loadch = [&](int cb_) {
#pragma unroll
    for (int s = 0; s < 4; ++s) {
      const float* kp = Kst + (size_t)(cb_ + s * 16) * D_DIM;
      const float* vp = Vst + (size_t)(cb_ + s * 16) * D_DIM;
      pk[2 * s]     = *(const f32x4*)(kp);
      pk[2 * s + 1] = *(const f32x4*)(kp + 4);
      pv[2 * s]     = *(const f32x4*)(vp);
      pv[2 * s + 1] = *(const f32x4*)(vp + 4);
    }
  };

  loadch(0);                        // prologue: chunk 0 in flight

  for (int ci = 0; ci < nch; ++ci) {
    const int cb = ci * CB;

    if (ci) {                       // LDS free: all waves done reading chunk ci-1
      asm volatile("s_waitcnt lgkmcnt(0)" ::: "memory");
      __builtin_amdgcn_s_barrier();
    }

    // ---- convert staged regs -> LDS (compiler inserts counted vmcnt for pk/pv)
#pragma unroll
    for (int s = 0; s < 4; ++s) {
      const int r = s * 16 + tr;
      *(bf16x8*)(Ksh + r * KS + cc * 8) = pack8(pk[2 * s], pk[2 * s + 1]);
      const int col = r ^ ((cc & 7) << 2);   // swizzle keyed on d>>3 == cc
      short* vt = VT + (cc * 8) * VS + col;
      unsigned int w0 = cvt_pk_bf16(pv[2 * s][0], pv[2 * s][1]);
      unsigned int w1 = cvt_pk_bf16(pv[2 * s][2], pv[2 * s][3]);
      unsigned int w2 = cvt_pk_bf16(pv[2 * s + 1][0], pv[2 * s + 1][1]);
      unsigned int w3 = cvt_pk_bf16(pv[2 * s + 1][2], pv[2 * s + 1][3]);
      vt[0 * VS] = (short)(w0);       vt[1 * VS] = (short)(w0 >> 16);
      vt[2 * VS] = (short)(w1);       vt[3 * VS] = (short)(w1 >> 16);
      vt[4 * VS] = (short)(w2);       vt[5 * VS] = (short)(w2 >> 16);
      vt[6 * VS] = (short)(w3);       vt[7 * VS] = (short)(w3 >> 16);
    }

    if (ci + 1 < nch) loadch(cb + CB);   // issue next chunk; in flight across
                                         // barrier + whole compute phase
    asm volatile("s_waitcnt lgkmcnt(0)" ::: "memory");
    __builtin_amdgcn_s_barrier();        // LDS ready (vmcnt NOT drained)

    // ---- WM loads: issued now, consumed after S^T MFMA chain (latency hidden)
    f32x4 wm[4];
#pragma unroll
    for (int j = 0; j < 4; ++j)
      wm[j] = *(const f32x4*)(WMq + cb + j * 16 + quad * 4);

#pragma unroll
    for (int ib = 0; ib < 2; ++ib) {
      const int kvb = cb + ib * 32;
      if (kvb >= kvlim) break;
      const int kloc = ib * 32;
      // ---- S^T: two 16-kv subtiles, A = K rows from LDS, B = Q frags ----
      f32x4 a0 = {0, 0, 0, 0}, a1 = {0, 0, 0, 0};
#pragma unroll
      for (int dc = 0; dc < 4; ++dc) {
        bf16x8 kf0 = *(const bf16x8*)(Ksh + (kloc + lq) * KS + dc * 32 + quad * 8);
        bf16x8 kf1 = *(const bf16x8*)(Ksh + (kloc + 16 + lq) * KS + dc * 32 + quad * 8);
        a0 = __builtin_amdgcn_mfma_f32_16x16x32_bf16(kf0, qf[dc], a0, 0, 0, 0);
        a1 = __builtin_amdgcn_mfma_f32_16x16x32_bf16(kf1, qf[dc], a1, 0, 0, 0);
      }
      // ---- scores: scale + window mask + valid-len mask ----
      const f32x4 wm0 = wm[ib * 2], wm1 = wm[ib * 2 + 1];
      float s0[4], s1[4];
      float mloc = -1e30f;
#pragma unroll
      for (int r = 0; r < 4; ++r) {
        int k0i = kvb + quad * 4 + r;
        s0[r] = (k0i < vlen)      ? a0[r] * SCALE + wm0[r] : -1e6f;
        s1[r] = (k0i + 16 < vlen) ? a1[r] * SCALE + wm1[r] : -1e6f;
        mloc = fmaxf(mloc, fmaxf(s0[r], s1[r]));
      }
      mloc = fmaxf(mloc, __shfl_xor(mloc, 16, 64));
      mloc = fmaxf(mloc, __shfl_xor(mloc, 32, 64));
      const float mnew  = fmaxf(mrun, mloc);
      const float alpha = __expf(mrun - mnew);
      mrun = mnew;

      float ev[8];
#pragma unroll
      for (int r = 0; r < 4; ++r) {
        ev[r]     = __expf(s0[r] - mnew);
        ev[4 + r] = __expf(s1[r] - mnew);
      }
      union { unsigned int u[4]; bf16x8 v; } pfu;
      pfu.u[0] = cvt_pk_bf16(ev[0], ev[1]);
      pfu.u[1] = cvt_pk_bf16(ev[2], ev[3]);
      pfu.u[2] = cvt_pk_bf16(ev[4], ev[5]);
      pfu.u[3] = cvt_pk_bf16(ev[6], ev[7]);
      float psum = 0.f;
#pragma unroll
      for (int t2 = 0; t2 < 4; ++t2) {    // sum the ROUNDED values (consistency)
        union { unsigned int i; float f; } lo, hi;
        lo.i = pfu.u[t2] << 16;
        hi.i = pfu.u[t2] & 0xffff0000u;
        psum += lo.f + hi.f;
      }
      psum += __shfl_xor(psum, 16, 64);
      psum += __shfl_xor(psum, 32, 64);
      lrun = lrun * alpha + psum;

      // alpha for O rows (O C-layout row = quad*4+reg; state lives at lane lq==row)
      float ar[4];
#pragma unroll
      for (int r = 0; r < 4; ++r) ar[r] = __shfl(alpha, quad * 4 + r, 64);

      const bf16x8 pf = pfu.v;   // [T0 p0..p3 | T1 p0..p3] == pi-permuted k order

#pragma unroll
      for (int t = 0; t < 8; ++t) {
        int d   = 16 * t + lq;
        int swz = ((d >> 3) & 7) << 2;
        s16x4 b0 = *(const s16x4*)(VT + d * VS + ((kloc + quad * 4) ^ swz));
        s16x4 b1 = *(const s16x4*)(VT + d * VS + ((kloc + 16 + quad * 4) ^ swz));
        bf16x8 bv = {b0[0], b0[1], b0[2], b0[3], b1[0], b1[1], b1[2], b1[3]};
        f32x4 ot = o[t];
#pragma unroll
        for (int r = 0; r < 4; ++r) ot[r] *= ar[r];
        o[t] = __builtin_amdgcn_mfma_f32_16x16x32_bf16(pf, bv, ot, 0, 0, 0);
      }
    }
  }

  // ---- epilogue: normalize by l (redistributed to O rows) and store fp32 ----
  float linv[4];
#pragma unroll
  for (int r = 0; r < 4; ++r) {
    float lr = __shfl(lrun, quad * 4 + r, 64);
    linv[r] = 1.f / lr;
  }
  float* On = O + (size_t)n * S_LEN * D_DIM;
#pragma unroll
  for (int t = 0; t < 8; ++t) {
#pragma unroll
    for (int r = 0; r < 4; ++r) {
      On[(size_t)(qw + quad * 4 + r) * D_DIM + 16 * t + lq] = o[t][r] * linv[r];
    }
  }
}

extern "C" void kernel_launch(void* const* d_in, const int* in_sizes, int n_in,
                              void* d_out, int out_size, void* d_ws, size_t ws_size,
                              hipStream_t stream) {
  const float* Q  = (const float*)d_in[0];
  const float* K  = (const float*)d_in[1];
  const float* V  = (const float*)d_in[2];
  const int*   VL = (const int*)d_in[3];
  const float* WM = (const float*)d_in[4];
  float* O = (float*)d_out;
  dim3 grid(256 * 8), block(256);
  attn_fused<<<grid, block, 0, stream>>>(Q, K, V, VL, WM, O);
}

// Round 2
// 253.170 us; speedup vs baseline: 1.3800x; 1.3800x over previous
//
#include <hip/hip_runtime.h>

typedef unsigned short u16;
using bf16x8 = __attribute__((ext_vector_type(8))) short;
using f32x4  = __attribute__((ext_vector_type(4))) float;
using s16x4  = __attribute__((ext_vector_type(4))) short;

#define S_LEN 512
#define D_DIM 128
#define CB    32                     // kv chunk staged in LDS (double-buffered)
#define KS    136                    // K LDS row stride (shorts): conflict-free b128
#define VS    36                     // VT LDS row stride (shorts): 72B rows
#define KBUF  (CB * KS)              // 4352 shorts per K buffer
#define VBUF  (D_DIM * VS)           // 4608 shorts per VT buffer
#define SCALE 0.08838834764831845f   // 1/sqrt(128)

// RNE f32 pair -> packed bf16x2 (1 instr, same rounding as round-trip f2b)
__device__ __forceinline__ unsigned int cvt_pk_bf16(float lo, float hi) {
  unsigned int r;
  asm("v_cvt_pk_bf16_f32 %0, %1, %2" : "=v"(r) : "v"(lo), "v"(hi));
  return r;
}
__device__ __forceinline__ bf16x8 pack8(f32x4 a, f32x4 b) {
  union { unsigned int u[4]; bf16x8 v; } r;
  r.u[0] = cvt_pk_bf16(a[0], a[1]);
  r.u[1] = cvt_pk_bf16(a[2], a[3]);
  r.u[2] = cvt_pk_bf16(b[0], b[1]);
  r.u[3] = cvt_pk_bf16(b[2], b[3]);
  return r.v;
}

// fp32 in / fp32 out. S^T = K.Q^T (A=K from LDS, B=Q regs); PV with pi-permuted
// packing. CB=32 double-buffered pipeline, ONE barrier per chunk:
//   iter i: issue loads(i+1) -> compute chunk i from buf -> write buf^1 -> barrier.
// Prefetch lives in 8 named f32x4 (32 VGPR), loaded unconditionally (clamped) so
// regalloc keeps it in registers (round-1 spill was caused by conditional array
// writes). Epilogue bounces O through LDS for fully-coalesced 512B row stores.
__global__ __launch_bounds__(256, 3)
void attn_fused(const float* __restrict__ Q, const float* __restrict__ K,
                const float* __restrict__ V, const int* __restrict__ VL,
                const float* __restrict__ WM, float* __restrict__ O) {
  __shared__ short smem[2 * KBUF + 2 * VBUF];   // 17920 shorts = 35840 B

  const int bid  = blockIdx.x;
  const int n    = (bid & 7) | ((bid >> 6) << 3);   // n%8 == bid%8 (XCD)
  const int qt   = (bid >> 3) & 7;
  const int tid  = threadIdx.x;
  const int wave = tid >> 6;
  const int L    = tid & 63;
  const int quad = L >> 4;
  const int lq   = L & 15;
  const int qw   = qt * 64 + wave * 16;   // wave's q base
  const int qg   = qw + lq;               // this lane's q row
  const int w    = (n >> 3) & 15;         // window index

  short* Ksh = smem;               // [2][CB][KS]
  short* VTb = smem + 2 * KBUF;    // [2][D_DIM][VS]

  const float* Qn  = Q + (size_t)n * S_LEN * D_DIM;
  const float* Kn  = K + (size_t)n * S_LEN * D_DIM;
  const float* Vn  = V + (size_t)n * S_LEN * D_DIM;
  const float* WMq = WM + ((size_t)w * S_LEN + qg) * S_LEN;

  const int vlen  = VL[n];
  const int kvlim = (vlen == 0) ? S_LEN : vlen;
  const int nch   = (kvlim + CB - 1) / CB;          // 1..16 chunks

  // Q fragments (B-operand): lane holds Q[qg][dc*32 + quad*8 + j], j=0..7
  bf16x8 qf[4];
#pragma unroll
  for (int dc = 0; dc < 4; ++dc) {
    const f32x4* qp = (const f32x4*)(Qn + (size_t)qg * D_DIM + dc * 32 + quad * 8);
    qf[dc] = pack8(qp[0], qp[1]);
  }

  f32x4 o[8];
#pragma unroll
  for (int t = 0; t < 8; ++t) o[t] = (f32x4){0.f, 0.f, 0.f, 0.f};
  float mrun = -1e30f, lrun = 0.f;

  // staging geometry: thread covers rows tr and tr+16 of the chunk at d-chunk cc
  const int tr = tid >> 4;          // 0..15
  const int cc = tid & 15;          // 8-float d-chunk
  const int colsw = (cc & 7) << 2;  // VT swizzle key (cc == d>>3)
  const float* Kst = Kn + (size_t)tr * D_DIM + cc * 8;
  const float* Vst = Vn + (size_t)tr * D_DIM + cc * 8;

  f32x4 k0a, k0b, k1a, k1b, v0a, v0b, v1a, v1b;   // 32 VGPR pipeline payload

#define STAGE_ISSUE(cb_) {                                              \
    const float* kp0 = Kst + (size_t)(cb_) * D_DIM;                     \
    const float* kp1 = kp0 + 16 * D_DIM;                                \
    const float* vp0 = Vst + (size_t)(cb_) * D_DIM;                     \
    const float* vp1 = vp0 + 16 * D_DIM;                                \
    k0a = ((const f32x4*)kp0)[0]; k0b = ((const f32x4*)kp0)[1];         \
    k1a = ((const f32x4*)kp1)[0]; k1b = ((const f32x4*)kp1)[1];         \
    v0a = ((const f32x4*)vp0)[0]; v0b = ((const f32x4*)vp0)[1];         \
    v1a = ((const f32x4*)vp1)[0]; v1b = ((const f32x4*)vp1)[1]; }

#define STAGE_WRITE(kd, vd) {                                           \
    *(bf16x8*)((kd) + tr * KS + cc * 8)        = pack8(k0a, k0b);       \
    *(bf16x8*)((kd) + (16 + tr) * KS + cc * 8) = pack8(k1a, k1b);       \
    short* vt0 = (vd) + (cc * 8) * VS + (tr ^ colsw);                   \
    short* vt1 = (vd) + (cc * 8) * VS + ((16 + tr) ^ colsw);            \
    unsigned int wa0 = cvt_pk_bf16(v0a[0], v0a[1]);                     \
    unsigned int wa1 = cvt_pk_bf16(v0a[2], v0a[3]);                     \
    unsigned int wa2 = cvt_pk_bf16(v0b[0], v0b[1]);                     \
    unsigned int wa3 = cvt_pk_bf16(v0b[2], v0b[3]);                     \
    vt0[0 * VS] = (short)(wa0);  vt0[1 * VS] = (short)(wa0 >> 16);      \
    vt0[2 * VS] = (short)(wa1);  vt0[3 * VS] = (short)(wa1 >> 16);      \
    vt0[4 * VS] = (short)(wa2);  vt0[5 * VS] = (short)(wa2 >> 16);      \
    vt0[6 * VS] = (short)(wa3);  vt0[7 * VS] = (short)(wa3 >> 16);      \
    unsigned int wb0 = cvt_pk_bf16(v1a[0], v1a[1]);                     \
    unsigned int wb1 = cvt_pk_bf16(v1a[2], v1a[3]);                     \
    unsigned int wb2 = cvt_pk_bf16(v1b[0], v1b[1]);                     \
    unsigned int wb3 = cvt_pk_bf16(v1b[2], v1b[3]);                     \
    vt1[0 * VS] = (short)(wb0);  vt1[1 * VS] = (short)(wb0 >> 16);      \
    vt1[2 * VS] = (short)(wb1);  vt1[3 * VS] = (short)(wb1 >> 16);      \
    vt1[4 * VS] = (short)(wb2);  vt1[5 * VS] = (short)(wb2 >> 16);      \
    vt1[6 * VS] = (short)(wb3);  vt1[7 * VS] = (short)(wb3 >> 16); }

  // ---- prologue: stage chunk 0 into buffer 0 ----
  STAGE_ISSUE(0);
  STAGE_WRITE(Ksh, VTb);            // compiler inserts the vmcnt wait
  asm volatile("s_waitcnt lgkmcnt(0)" ::: "memory");
  __builtin_amdgcn_s_barrier();

  int buf = 0;
  for (int ci = 0; ci < nch; ++ci) {
    const int cb   = ci * CB;
    const int cpre = (ci + 1 < nch ? ci + 1 : nch - 1) * CB;  // clamped, uniform

    // issue next chunk's loads: in flight across the whole compute phase
    STAGE_ISSUE(cpre);
    // WM rows for THIS chunk: consumed after the QK^T MFMA chain
    f32x4 wm0 = *(const f32x4*)(WMq + cb + quad * 4);
    f32x4 wm1 = *(const f32x4*)(WMq + cb + 16 + quad * 4);
    __builtin_amdgcn_sched_barrier(0);   // keep loads above compute

    // ---- compute chunk ci from buf ----
    const short* Kc = Ksh + buf * KBUF;
    const short* Vc = VTb + buf * VBUF;

    f32x4 a0 = {0, 0, 0, 0}, a1 = {0, 0, 0, 0};
#pragma unroll
    for (int dc = 0; dc < 4; ++dc) {
      bf16x8 kf0 = *(const bf16x8*)(Kc + lq * KS + dc * 32 + quad * 8);
      bf16x8 kf1 = *(const bf16x8*)(Kc + (16 + lq) * KS + dc * 32 + quad * 8);
      a0 = __builtin_amdgcn_mfma_f32_16x16x32_bf16(kf0, qf[dc], a0, 0, 0, 0);
      a1 = __builtin_amdgcn_mfma_f32_16x16x32_bf16(kf1, qf[dc], a1, 0, 0, 0);
    }
    // ---- scores: scale + window mask + valid-len mask (-1e6 like ref) ----
    float s0[4], s1[4];
    float mloc = -1e30f;
#pragma unroll
    for (int r = 0; r < 4; ++r) {
      int k0i = cb + quad * 4 + r;
      s0[r] = (k0i < vlen)      ? a0[r] * SCALE + wm0[r] : -1e6f;
      s1[r] = (k0i + 16 < vlen) ? a1[r] * SCALE + wm1[r] : -1e6f;
      mloc = fmaxf(mloc, fmaxf(s0[r], s1[r]));
    }
    mloc = fmaxf(mloc, __shfl_xor(mloc, 16, 64));
    mloc = fmaxf(mloc, __shfl_xor(mloc, 32, 64));
    const float mnew  = fmaxf(mrun, mloc);
    const float alpha = __expf(mrun - mnew);
    mrun = mnew;

    float ev[8];
#pragma unroll
    for (int r = 0; r < 4; ++r) {
      ev[r]     = __expf(s0[r] - mnew);
      ev[4 + r] = __expf(s1[r] - mnew);
    }
    union { unsigned int u[4]; bf16x8 v; } pfu;
    pfu.u[0] = cvt_pk_bf16(ev[0], ev[1]);
    pfu.u[1] = cvt_pk_bf16(ev[2], ev[3]);
    pfu.u[2] = cvt_pk_bf16(ev[4], ev[5]);
    pfu.u[3] = cvt_pk_bf16(ev[6], ev[7]);
    float psum = 0.f;
#pragma unroll
    for (int t2 = 0; t2 < 4; ++t2) {    // sum the ROUNDED values (consistency)
      union { unsigned int i; float f; } lo, hi;
      lo.i = pfu.u[t2] << 16;
      hi.i = pfu.u[t2] & 0xffff0000u;
      psum += lo.f + hi.f;
    }
    psum += __shfl_xor(psum, 16, 64);
    psum += __shfl_xor(psum, 32, 64);
    lrun = lrun * alpha + psum;

    // alpha for O rows (O C-layout row = quad*4+reg; state lives at lane lq==row)
    float ar[4];
#pragma unroll
    for (int r = 0; r < 4; ++r) ar[r] = __shfl(alpha, quad * 4 + r, 64);

    const bf16x8 pf = pfu.v;   // [T0 p0..p3 | T1 p0..p3] == pi-permuted k order

#pragma unroll
    for (int t = 0; t < 8; ++t) {
      int d   = 16 * t + lq;
      int swz = ((d >> 3) & 7) << 2;
      s16x4 b0 = *(const s16x4*)(Vc + d * VS + ((quad * 4) ^ swz));
      s16x4 b1 = *(const s16x4*)(Vc + d * VS + ((16 + quad * 4) ^ swz));
      bf16x8 bv = {b0[0], b0[1], b0[2], b0[3], b1[0], b1[1], b1[2], b1[3]};
      f32x4 ot = o[t];
#pragma unroll
      for (int r = 0; r < 4; ++r) ot[r] *= ar[r];
      o[t] = __builtin_amdgcn_mfma_f32_16x16x32_bf16(pf, bv, ot, 0, 0, 0);
    }

    __builtin_amdgcn_sched_barrier(0);   // keep write phase below compute
    // ---- write staged regs (chunk ci+1) to the other buffer ----
    STAGE_WRITE(Ksh + (buf ^ 1) * KBUF, VTb + (buf ^ 1) * VBUF);
    asm volatile("s_waitcnt lgkmcnt(0)" ::: "memory");
    __builtin_amdgcn_s_barrier();
    buf ^= 1;
  }

  // ---- epilogue: normalize, bounce O through LDS, coalesced row stores ----
  float linv[4];
#pragma unroll
  for (int r = 0; r < 4; ++r) {
    float lr = __shfl(lrun, quad * 4 + r, 64);
    linv[r] = 1.f / lr;
  }
  // per-wave private region: 16 rows x 132 floats (pad keeps b128 aligned, 2-way banks)
  float* ow = (float*)smem + wave * (16 * 132);
#pragma unroll
  for (int t = 0; t < 8; ++t) {
#pragma unroll
    for (int r = 0; r < 4; ++r) {
      ow[(quad * 4 + r) * 132 + 16 * t + lq] = o[t][r] * linv[r];
    }
  }
  asm volatile("s_waitcnt lgkmcnt(0)" ::: "memory");
  float* On = O + (size_t)n * S_LEN * D_DIM;
  const int half = L >> 5;
  const int c4   = (L & 31) * 4;
#pragma unroll
  for (int p = 0; p < 8; ++p) {
    int row = 2 * p + half;
    f32x4 v = *(const f32x4*)(ow + row * 132 + c4);
    *(f32x4*)(On + (size_t)(qw + row) * D_DIM + c4) = v;
  }
}

extern "C" void kernel_launch(void* const* d_in, const int* in_sizes, int n_in,
                              void* d_out, int out_size, void* d_ws, size_t ws_size,
                              hipStream_t stream) {
  const float* Q  = (const float*)d_in[0];
  const float* K  = (const float*)d_in[1];
  const float* V  = (const float*)d_in[2];
  const int*   VL = (const int*)d_in[3];
  const float* WM = (const float*)d_in[4];
  float* O = (float*)d_out;
  dim3 grid(256 * 8), block(256);
  attn_fused<<<grid, block, 0, stream>>>(Q, K, V, VL, WM, O);
}

// Round 4
// 247.737 us; speedup vs baseline: 1.4102x; 1.0219x over previous
//
#include <hip/hip_runtime.h>

typedef unsigned short u16;
using bf16x8 = __attribute__((ext_vector_type(8))) short;
using f32x4  = __attribute__((ext_vector_type(4))) float;
using s16x4  = __attribute__((ext_vector_type(4))) short;

#define S_LEN 512
#define D_DIM 128
#define CB    32                     // kv chunk staged in LDS (double-buffered)
#define KS    136                    // K LDS row stride (shorts): conflict-free b128
#define VS    36                     // VT LDS row stride (shorts): 72B rows
#define KBUF  (CB * KS)              // 4352 shorts per K buffer
#define VBUF  (D_DIM * VS)           // 4608 shorts per VT buffer
#define SCALE 0.08838834764831845f   // 1/sqrt(128)

// RNE f32 pair -> packed bf16x2 (1 instr, same rounding as round-trip f2b)
__device__ __forceinline__ unsigned int cvt_pk_bf16(float lo, float hi) {
  unsigned int r;
  asm("v_cvt_pk_bf16_f32 %0, %1, %2" : "=v"(r) : "v"(lo), "v"(hi));
  return r;
}
__device__ __forceinline__ bf16x8 pack8(f32x4 a, f32x4 b) {
  union { unsigned int u[4]; bf16x8 v; } r;
  r.u[0] = cvt_pk_bf16(a[0], a[1]);
  r.u[1] = cvt_pk_bf16(a[2], a[3]);
  r.u[2] = cvt_pk_bf16(b[0], b[1]);
  r.u[3] = cvt_pk_bf16(b[2], b[3]);
  return r.v;
}

// fp32 in / fp32 out. S^T = K.Q^T (A=K from LDS, B=Q regs); PV with pi-permuted
// packing. CB=32, LDS double-buffered, TWO register payloads (A=even chunks,
// B=odd) -> 2-deep pipeline: loads for chunk c+2 issued at iter c, written at
// end of iter c+1, so ~2 compute phases in flight (> worst-case HBM latency)
// and the vmcnt wait at STAGE_WRITE is ~free. One barrier per chunk.
// Softmax: UNCONDITIONAL online rescale (round-2 semantics; T13 reverted --
// it was the corruption suspect in round 3).
__global__ __launch_bounds__(256, 3)
void attn_fused(const float* __restrict__ Q, const float* __restrict__ K,
                const float* __restrict__ V, const int* __restrict__ VL,
                const float* __restrict__ WM, float* __restrict__ O) {
  __shared__ short smem[2 * KBUF + 2 * VBUF];   // 17920 shorts = 35840 B

  const int bid  = blockIdx.x;
  const int n    = (bid & 7) | ((bid >> 6) << 3);   // n%8 == bid%8 (XCD)
  const int qt   = (bid >> 3) & 7;
  const int tid  = threadIdx.x;
  const int wave = tid >> 6;
  const int L    = tid & 63;
  const int quad = L >> 4;
  const int lq   = L & 15;
  const int qw   = qt * 64 + wave * 16;   // wave's q base
  const int qg   = qw + lq;               // this lane's q row
  const int w    = (n >> 3) & 15;         // window index

  short* K0 = smem;                 // even-chunk K buffer
  short* K1 = smem + KBUF;          // odd-chunk K buffer
  short* V0 = smem + 2 * KBUF;      // even-chunk VT buffer
  short* V1 = V0 + VBUF;            // odd-chunk VT buffer

  const float* Qn  = Q + (size_t)n * S_LEN * D_DIM;
  const float* Kn  = K + (size_t)n * S_LEN * D_DIM;
  const float* Vn  = V + (size_t)n * S_LEN * D_DIM;
  const float* WMq = WM + ((size_t)w * S_LEN + qg) * S_LEN;

  const int vlen  = VL[n];
  const int kvlim = (vlen == 0) ? S_LEN : vlen;
  const int nch   = (kvlim + CB - 1) / CB;          // 1..16 chunks (block-uniform)
  const int nchm1 = nch - 1;

  // Q fragments (B-operand): lane holds Q[qg][dc*32 + quad*8 + j], j=0..7
  bf16x8 qf[4];
#pragma unroll
  for (int dc = 0; dc < 4; ++dc) {
    const f32x4* qp = (const f32x4*)(Qn + (size_t)qg * D_DIM + dc * 32 + quad * 8);
    qf[dc] = pack8(qp[0], qp[1]);
  }

  f32x4 o[8];
#pragma unroll
  for (int t = 0; t < 8; ++t) o[t] = (f32x4){0.f, 0.f, 0.f, 0.f};
  float mrun = -1e30f, lrun = 0.f;

  // staging geometry: thread covers rows tr and tr+16 of the chunk at d-chunk cc
  const int tr = tid >> 4;          // 0..15
  const int cc = tid & 15;          // 8-float d-chunk
  const int colsw = (cc & 7) << 2;  // VT swizzle key (cc == d>>3)
  const float* Kst = Kn + (size_t)tr * D_DIM + cc * 8;
  const float* Vst = Vn + (size_t)tr * D_DIM + cc * 8;

  // two named register payloads (rule #20: no arrays, no conditional writes)
  f32x4 Ak0a, Ak0b, Ak1a, Ak1b, Av0a, Av0b, Av1a, Av1b;
  f32x4 Bk0a, Bk0b, Bk1a, Bk1b, Bv0a, Bv0b, Bv1a, Bv1b;

#define STAGE_ISSUE(P, cb_) {                                           \
    const float* kp0 = Kst + (size_t)(cb_) * D_DIM;                     \
    const float* kp1 = kp0 + 16 * D_DIM;                                \
    const float* vp0 = Vst + (size_t)(cb_) * D_DIM;                     \
    const float* vp1 = vp0 + 16 * D_DIM;                                \
    P##k0a = ((const f32x4*)kp0)[0]; P##k0b = ((const f32x4*)kp0)[1];   \
    P##k1a = ((const f32x4*)kp1)[0]; P##k1b = ((const f32x4*)kp1)[1];   \
    P##v0a = ((const f32x4*)vp0)[0]; P##v0b = ((const f32x4*)vp0)[1];   \
    P##v1a = ((const f32x4*)vp1)[0]; P##v1b = ((const f32x4*)vp1)[1]; }

#define STAGE_WRITE(P, kd, vd) {                                        \
    *(bf16x8*)((kd) + tr * KS + cc * 8)        = pack8(P##k0a, P##k0b); \
    *(bf16x8*)((kd) + (16 + tr) * KS + cc * 8) = pack8(P##k1a, P##k1b); \
    short* vt0 = (vd) + (cc * 8) * VS + (tr ^ colsw);                   \
    short* vt1 = (vd) + (cc * 8) * VS + ((16 + tr) ^ colsw);            \
    unsigned int wa0 = cvt_pk_bf16(P##v0a[0], P##v0a[1]);               \
    unsigned int wa1 = cvt_pk_bf16(P##v0a[2], P##v0a[3]);               \
    unsigned int wa2 = cvt_pk_bf16(P##v0b[0], P##v0b[1]);               \
    unsigned int wa3 = cvt_pk_bf16(P##v0b[2], P##v0b[3]);               \
    vt0[0 * VS] = (short)(wa0);  vt0[1 * VS] = (short)(wa0 >> 16);      \
    vt0[2 * VS] = (short)(wa1);  vt0[3 * VS] = (short)(wa1 >> 16);      \
    vt0[4 * VS] = (short)(wa2);  vt0[5 * VS] = (short)(wa2 >> 16);      \
    vt0[6 * VS] = (short)(wa3);  vt0[7 * VS] = (short)(wa3 >> 16);      \
    unsigned int wb0 = cvt_pk_bf16(P##v1a[0], P##v1a[1]);               \
    unsigned int wb1 = cvt_pk_bf16(P##v1a[2], P##v1a[3]);               \
    unsigned int wb2 = cvt_pk_bf16(P##v1b[0], P##v1b[1]);               \
    unsigned int wb3 = cvt_pk_bf16(P##v1b[2], P##v1b[3]);               \
    vt1[0 * VS] = (short)(wb0);  vt1[1 * VS] = (short)(wb0 >> 16);      \
    vt1[2 * VS] = (short)(wb1);  vt1[3 * VS] = (short)(wb1 >> 16);      \
    vt1[4 * VS] = (short)(wb2);  vt1[5 * VS] = (short)(wb2 >> 16);      \
    vt1[6 * VS] = (short)(wb3);  vt1[7 * VS] = (short)(wb3 >> 16); }

  auto compute_chunk = [&](int cb, const short* Kc, const short* Vc) {
    // WM rows for this chunk: issued first, consumed after the QK^T MFMA chain
    f32x4 wm0 = *(const f32x4*)(WMq + cb + quad * 4);
    f32x4 wm1 = *(const f32x4*)(WMq + cb + 16 + quad * 4);

    // ---- S^T: two 16-kv subtiles, A = K rows from LDS, B = Q frags ----
    f32x4 a0 = {0, 0, 0, 0}, a1 = {0, 0, 0, 0};
#pragma unroll
    for (int dc = 0; dc < 4; ++dc) {
      bf16x8 kf0 = *(const bf16x8*)(Kc + lq * KS + dc * 32 + quad * 8);
      bf16x8 kf1 = *(const bf16x8*)(Kc + (16 + lq) * KS + dc * 32 + quad * 8);
      a0 = __builtin_amdgcn_mfma_f32_16x16x32_bf16(kf0, qf[dc], a0, 0, 0, 0);
      a1 = __builtin_amdgcn_mfma_f32_16x16x32_bf16(kf1, qf[dc], a1, 0, 0, 0);
    }
    // ---- scores: scale + window mask + valid-len mask (-1e6 like ref) ----
    float s0[4], s1[4];
    float mloc = -1e30f;
#pragma unroll
    for (int r = 0; r < 4; ++r) {
      int k0i = cb + quad * 4 + r;
      s0[r] = (k0i < vlen)      ? a0[r] * SCALE + wm0[r] : -1e6f;
      s1[r] = (k0i + 16 < vlen) ? a1[r] * SCALE + wm1[r] : -1e6f;
      mloc = fmaxf(mloc, fmaxf(s0[r], s1[r]));
    }
    mloc = fmaxf(mloc, __shfl_xor(mloc, 16, 64));
    mloc = fmaxf(mloc, __shfl_xor(mloc, 32, 64));
    const float mnew  = fmaxf(mrun, mloc);
    const float alpha = __expf(mrun - mnew);
    mrun = mnew;

    float ev[8];
#pragma unroll
    for (int r = 0; r < 4; ++r) {
      ev[r]     = __expf(s0[r] - mnew);
      ev[4 + r] = __expf(s1[r] - mnew);
    }
    union { unsigned int u[4]; bf16x8 v; } pfu;
    pfu.u[0] = cvt_pk_bf16(ev[0], ev[1]);
    pfu.u[1] = cvt_pk_bf16(ev[2], ev[3]);
    pfu.u[2] = cvt_pk_bf16(ev[4], ev[5]);
    pfu.u[3] = cvt_pk_bf16(ev[6], ev[7]);
    float psum = 0.f;
#pragma unroll
    for (int t2 = 0; t2 < 4; ++t2) {    // sum the ROUNDED values (consistency)
      union { unsigned int i; float f; } lo, hi;
      lo.i = pfu.u[t2] << 16;
      hi.i = pfu.u[t2] & 0xffff0000u;
      psum += lo.f + hi.f;
    }
    psum += __shfl_xor(psum, 16, 64);
    psum += __shfl_xor(psum, 32, 64);
    lrun = lrun * alpha + psum;

    // alpha for O rows (O C-layout row = quad*4+reg; state lives at lane lq==row)
    float ar[4];
#pragma unroll
    for (int r = 0; r < 4; ++r) ar[r] = __shfl(alpha, quad * 4 + r, 64);

    const bf16x8 pf = pfu.v;   // [T0 p0..p3 | T1 p0..p3] == pi-permuted k order
#pragma unroll
    for (int t = 0; t < 8; ++t) {
      int d   = 16 * t + lq;
      int swz = ((d >> 3) & 7) << 2;
      s16x4 b0 = *(const s16x4*)(Vc + d * VS + ((quad * 4) ^ swz));
      s16x4 b1 = *(const s16x4*)(Vc + d * VS + ((16 + quad * 4) ^ swz));
      bf16x8 bv = {b0[0], b0[1], b0[2], b0[3], b1[0], b1[1], b1[2], b1[3]};
      f32x4 ot = o[t];
#pragma unroll
      for (int r = 0; r < 4; ++r) ot[r] *= ar[r];
      o[t] = __builtin_amdgcn_mfma_f32_16x16x32_bf16(pf, bv, ot, 0, 0, 0);
    }
  };

  // ---- prologue: issue chunk 0 (A) and chunk 1 (B), write chunk 0 ----
  STAGE_ISSUE(A, 0);
  {
    const int c1 = (1 <= nchm1 ? 1 : nchm1) * CB;
    STAGE_ISSUE(B, c1);
  }
  STAGE_WRITE(A, K0, V0);           // counted vmcnt: waits A, leaves B in flight
  asm volatile("s_waitcnt lgkmcnt(0)" ::: "memory");
  __builtin_amdgcn_s_barrier();

  // ---- main loop, unrolled x2: even chunks in (K0,V0)/payload A, odd in (K1,V1)/B
  int ci = 0;
  for (;;) {
    {  // even chunk ci
      const int cp = (ci + 2 <= nchm1 ? ci + 2 : nchm1) * CB;
      STAGE_ISSUE(A, cp);           // chunk ci+2, in flight ~2 iterations
      __builtin_amdgcn_sched_barrier(0);
      compute_chunk(ci * CB, K0, V0);
      if (ci + 1 >= nch) break;
      __builtin_amdgcn_sched_barrier(0);
      STAGE_WRITE(B, K1, V1);       // waits B (issued 2 iters ago): ~free
      asm volatile("s_waitcnt lgkmcnt(0)" ::: "memory");
      __builtin_amdgcn_s_barrier();
    }
    {  // odd chunk ci+1
      const int cp = (ci + 3 <= nchm1 ? ci + 3 : nchm1) * CB;
      STAGE_ISSUE(B, cp);
      __builtin_amdgcn_sched_barrier(0);
      compute_chunk((ci + 1) * CB, K1, V1);
      if (ci + 2 >= nch) break;
      __builtin_amdgcn_sched_barrier(0);
      STAGE_WRITE(A, K0, V0);
      asm volatile("s_waitcnt lgkmcnt(0)" ::: "memory");
      __builtin_amdgcn_s_barrier();
    }
    ci += 2;
  }

  // loop exits via break (no trailing barrier): ensure no wave still reads K/V
  // LDS before the epilogue overwrites it.
  asm volatile("s_waitcnt lgkmcnt(0)" ::: "memory");
  __builtin_amdgcn_s_barrier();

  // ---- epilogue: normalize, bounce O through LDS, coalesced row stores ----
  float linv[4];
#pragma unroll
  for (int r = 0; r < 4; ++r) {
    float lr = __shfl(lrun, quad * 4 + r, 64);
    linv[r] = 1.f / lr;
  }
  // per-wave private region: 16 rows x 132 floats (pad keeps b128 aligned)
  float* ow = (float*)smem + wave * (16 * 132);
#pragma unroll
  for (int t = 0; t < 8; ++t) {
#pragma unroll
    for (int r = 0; r < 4; ++r) {
      ow[(quad * 4 + r) * 132 + 16 * t + lq] = o[t][r] * linv[r];
    }
  }
  asm volatile("s_waitcnt lgkmcnt(0)" ::: "memory");
  float* On = O + (size_t)n * S_LEN * D_DIM;
  const int half = L >> 5;
  const int c4   = (L & 31) * 4;
#pragma unroll
  for (int p = 0; p < 8; ++p) {
    int row = 2 * p + half;
    f32x4 v = *(const f32x4*)(ow + row * 132 + c4);
    *(f32x4*)(On + (size_t)(qw + row) * D_DIM + c4) = v;
  }
}

extern "C" void kernel_launch(void* const* d_in, const int* in_sizes, int n_in,
                              void* d_out, int out_size, void* d_ws, size_t ws_size,
                              hipStream_t stream) {
  const float* Q  = (const float*)d_in[0];
  const float* K  = (const float*)d_in[1];
  const float* V  = (const float*)d_in[2];
  const int*   VL = (const int*)d_in[3];
  const float* WM = (const float*)d_in[4];
  float* O = (float*)d_out;
  dim3 grid(256 * 8), block(256);
  attn_fused<<<grid, block, 0, stream>>>(Q, K, V, VL, WM, O);
}